// Round 8
// baseline (273.786 us; speedup 1.0000x reference)
//
#include <hip/hip_runtime.h>
#include <math.h>
#include <stdint.h>

// Router: x[4,4096,2048] f32, W[64,2048] f32
// out f32 concat: topk_weight[16384,2], topk_idx[16384,2] (as float), aux_loss[1]
//
// ROUND 8 = A/B measurement round:
//   A: router_mfma   — bit-identical to round-7 kernel, writes real outputs.
//   B: router_mfma_b — variant (x hi/lo planes, no A-perms; dual accumulators),
//      writes to d_ws scratch only. R_B = dur_r8 - dur_r7 - ~2us.
// Scaling: x*256, W*1024 (exact pow2), logits /2^18 in epilogue (exact).

#define D_MODEL 2048
#define NE      64
#define N_ROWS  16384
#define ALPHA   0.01f
#define BR      32
#define BK      64
#define NCH     (D_MODEL / BK)   // 32
#define THREADS 512

typedef _Float16 f16x8 __attribute__((ext_vector_type(8)));
typedef float    f32x4 __attribute__((ext_vector_type(4)));

union U4 { uint32_t u[4]; uint4 v; };
union F8 { uint32_t u[4]; f16x8 v; };

__device__ __forceinline__ uint32_t pack_hl(float xs) {
    _Float16 h = (_Float16)xs;
    float hf = (float)h;
    _Float16 l = (_Float16)(xs - hf);
    union { _Float16 f; uint16_t b; } ch, cl;
    ch.f = h; cl.f = l;
    return (uint32_t)ch.b | ((uint32_t)cl.b << 16);
}

#define GLD16(src, dst) __builtin_amdgcn_global_load_lds( \
    (const __attribute__((address_space(1))) void*)(src), \
    (__attribute__((address_space(3))) void*)(dst), 16, 0, 0)

// counted-vmcnt raw barriers (T4-lite): keep px in flight across the barrier.
#define BAR_KEEP1() { asm volatile("s_waitcnt vmcnt(1) lgkmcnt(0)" ::: "memory"); \
                      __builtin_amdgcn_s_barrier(); \
                      __builtin_amdgcn_sched_barrier(0); }
#define BAR_FULL()  { asm volatile("s_waitcnt vmcnt(0) lgkmcnt(0)" ::: "memory"); \
                      __builtin_amdgcn_s_barrier(); \
                      __builtin_amdgcn_sched_barrier(0); }

// ---- k0: W -> two f16 planes per 64-k chunk, swizzled ----
// chunk c (k = c*64 + kl): plane row e = 8 slots x 16B (8 f16 each), slot ^= (e&7).
// img u32 layout: [c][0..2047] = hi plane, [c][2048..4095] = lo plane.
__global__ __launch_bounds__(256)
void w_prep(const float* __restrict__ W, uint32_t* __restrict__ img) {
    const int idx = blockIdx.x * 256 + threadIdx.x;   // 0..65535
    const int e = idx >> 10, kp = (idx & 1023) * 2;   // even k pair
    const float w0 = W[(size_t)e * D_MODEL + kp]     * 1024.0f;
    const float w1 = W[(size_t)e * D_MODEL + kp + 1] * 1024.0f;
    _Float16 h0 = (_Float16)w0; _Float16 l0 = (_Float16)(w0 - (float)h0);
    _Float16 h1 = (_Float16)w1; _Float16 l1 = (_Float16)(w1 - (float)h1);
    union { _Float16 f[2]; uint32_t u; } ph, pl;
    ph.f[0] = h0; ph.f[1] = h1;
    pl.f[0] = l0; pl.f[1] = l1;
    const int c = kp >> 6, kl = kp & 63;
    const int slot = kl >> 3, uo = (kl & 7) >> 1;
    const int so = (e * 8 + (slot ^ (e & 7))) * 4 + uo;   // u32 index in plane
    uint32_t* base = img + (size_t)c * 4096;
    base[so]        = ph.u;
    base[2048 + so] = pl.u;
}

// ---- A: round-7 kernel, unchanged (validated output path) ----
__global__ __launch_bounds__(THREADS, 4)
void router_mfma(const float* __restrict__ x, const uint32_t* __restrict__ wimg,
                 float* __restrict__ out_w, float* __restrict__ out_i,
                 float* __restrict__ g_pi, float* __restrict__ g_cnt) {
    __shared__ __align__(16) uint32_t sm[2 * 2048 + 2 * 4096];
    __shared__ float apx[8][NE], acn[8][NE];

    uint32_t* lx = sm;            // [2][2048]
    uint32_t* lw = sm + 4096;     // [2][4096]
    float*    ll = (float*)sm;    // logits [32][68], aliased after final barrier

    const int tid  = threadIdx.x;
    const int lane = tid & 63;
    const int wv   = tid >> 6;          // 0..7
    const int rb   = blockIdx.x * BR;

    const int srow = tid >> 4;          // 0..31
    const int ssu  = tid & 15;          // 0..15, covers kl = ssu*4..+3
    const float* xg = x + (size_t)(rb + srow) * D_MODEL + ssu * 4;
    const int xw_off = (srow * 16 + (ssu ^ (srow & 7))) * 4;

    const int mt = wv >> 2, nt = wv & 3;
    const int arow = mt * 16 + (lane & 15);
    const int be   = nt * 16 + (lane & 15);
    const int kq   = lane >> 4;
    const int ap = arow & 7, bp = be & 7;

    f32x4 acc = {0.f, 0.f, 0.f, 0.f};

    {
        const float4 p0 = *(const float4*)xg;
        uint4 w0;
        w0.x = pack_hl(p0.x * 256.f); w0.y = pack_hl(p0.y * 256.f);
        w0.z = pack_hl(p0.z * 256.f); w0.w = pack_hl(p0.w * 256.f);
        *(uint4*)(lx + xw_off) = w0;
        GLD16(wimg + (size_t)tid * 4,         lw + tid * 4);
        GLD16(wimg + (size_t)(tid + 512) * 4, lw + (tid + 512) * 4);
    }
    float4 px = *(const float4*)(xg + BK);
    BAR_KEEP1();

    for (int t = 0; t < NCH; ++t) {
        const int buf = t & 1, nbuf = buf ^ 1;

        if (t + 1 < NCH) {
            const uint32_t* ws = wimg + (size_t)(t + 1) * 4096;
            GLD16(ws + (size_t)tid * 4,         lw + nbuf * 4096 + tid * 4);
            GLD16(ws + (size_t)(tid + 512) * 4, lw + nbuf * 4096 + (tid + 512) * 4);
        }

        const uint32_t* lxb = lx + buf * 2048;
        const uint32_t* lwb = lw + buf * 4096;
        #pragma unroll
        for (int ks = 0; ks < 2; ++ks) {
            const int su0 = ks * 8 + kq * 2;
            const int sb  = ks * 4 + kq;
            U4 a0, a1;
            a0.v = *(const uint4*)(lxb + (arow * 16 + ( su0      ^ ap)) * 4);
            a1.v = *(const uint4*)(lxb + (arow * 16 + ((su0 + 1) ^ ap)) * 4);
            F8 bh, bl;
            bh.v = *(const f16x8*)(lwb +        (be * 8 + (sb ^ bp)) * 4);
            bl.v = *(const f16x8*)(lwb + 2048 + (be * 8 + (sb ^ bp)) * 4);
            F8 ah, al;
            #pragma unroll
            for (int p = 0; p < 2; ++p) {
                ah.u[p]     = __builtin_amdgcn_perm(a0.u[2*p+1], a0.u[2*p], 0x05040100u);
                al.u[p]     = __builtin_amdgcn_perm(a0.u[2*p+1], a0.u[2*p], 0x07060302u);
                ah.u[2 + p] = __builtin_amdgcn_perm(a1.u[2*p+1], a1.u[2*p], 0x05040100u);
                al.u[2 + p] = __builtin_amdgcn_perm(a1.u[2*p+1], a1.u[2*p], 0x07060302u);
            }
            acc = __builtin_amdgcn_mfma_f32_16x16x32_f16(ah.v, bh.v, acc, 0, 0, 0);
            acc = __builtin_amdgcn_mfma_f32_16x16x32_f16(ah.v, bl.v, acc, 0, 0, 0);
            acc = __builtin_amdgcn_mfma_f32_16x16x32_f16(al.v, bh.v, acc, 0, 0, 0);
        }

        if (t + 1 < NCH) {
            uint4 wo;
            wo.x = pack_hl(px.x * 256.f); wo.y = pack_hl(px.y * 256.f);
            wo.z = pack_hl(px.z * 256.f); wo.w = pack_hl(px.w * 256.f);
            *(uint4*)(lx + nbuf * 2048 + xw_off) = wo;
            if (t + 2 < NCH) px = *(const float4*)(xg + (size_t)(t + 2) * BK);
        }

        if (t + 2 < NCH) { BAR_KEEP1(); } else { BAR_FULL(); }
    }

    #pragma unroll
    for (int r = 0; r < 4; ++r) {
        const int row = mt * 16 + kq * 4 + r;
        ll[row * 68 + be] = acc[r] * (1.0f / 262144.0f);
    }
    __syncthreads();

    float pi_acc = 0.f, cnt_acc = 0.f;
    for (int rr = 0; rr < 4; ++rr) {
        const int row = wv * 4 + rr;
        const float lg = ll[row * 68 + lane];

        float m = lg;
        #pragma unroll
        for (int off = 32; off; off >>= 1) m = fmaxf(m, __shfl_xor(m, off));
        const float e = expf(lg - m);
        float s = e;
        #pragma unroll
        for (int off = 32; off; off >>= 1) s += __shfl_xor(s, off);
        const float score = e / s;

        float v1 = score; int i1 = lane;
        #pragma unroll
        for (int off = 32; off; off >>= 1) {
            const float ov = __shfl_xor(v1, off);
            const int   oi = __shfl_xor(i1, off);
            if (ov > v1 || (ov == v1 && oi < i1)) { v1 = ov; i1 = oi; }
        }
        float v2 = (lane == i1) ? -1.f : score; int i2 = lane;
        #pragma unroll
        for (int off = 32; off; off >>= 1) {
            const float ov = __shfl_xor(v2, off);
            const int   oi = __shfl_xor(i2, off);
            if (ov > v2 || (ov == v2 && oi < i2)) { v2 = ov; i2 = oi; }
        }

        if (lane == 0) {
            const int grow = rb + row;
            const float denom = v1 + v2 + 1e-9f;
            out_w[grow * 2 + 0] = v1 / denom;
            out_w[grow * 2 + 1] = v2 / denom;
            out_i[grow * 2 + 0] = (float)i1;
            out_i[grow * 2 + 1] = (float)i2;
        }
        pi_acc  += score;
        cnt_acc += (float)((lane == i1) + (lane == i2));
    }

    apx[wv][lane] = pi_acc;
    acn[wv][lane] = cnt_acc;
    __syncthreads();

    if (tid < NE) {
        float p = 0.f, c = 0.f;
        #pragma unroll
        for (int w = 0; w < 8; ++w) { p += apx[w][tid]; c += acn[w][tid]; }
        atomicAdd(&g_pi[tid],  p);
        atomicAdd(&g_cnt[tid], c);
    }
}

// ---- B: variant under test (scratch outputs, not validated this round) ----
// x staged as separate hi/lo f16 planes (A-frags = direct ds_read_b128, zero perms);
// dual accumulators (ks=0 -> accA, ks=1 -> accB) break the 6-long MFMA chain.
__global__ __launch_bounds__(THREADS, 4)
void router_mfma_b(const float* __restrict__ x, const uint32_t* __restrict__ wimg,
                   float* __restrict__ out_w, float* __restrict__ out_i,
                   float* __restrict__ g_pi, float* __restrict__ g_cnt) {
    __shared__ __align__(16) uint32_t sm[2 * 2048 + 2 * 4096];
    __shared__ float apx[8][NE], acn[8][NE];

    uint32_t* lx = sm;            // [2][2048]: per buf [0..1023]=hi plane, [1024..2047]=lo
    uint32_t* lw = sm + 4096;     // [2][4096]: W planes (hi 2048, lo 2048 per buf)
    float*    ll = (float*)sm;

    const int tid  = threadIdx.x;
    const int lane = tid & 63;
    const int wv   = tid >> 6;
    const int rb   = blockIdx.x * BR;

    // staging map: thread -> (row, 4-k segment); plane rows are 32 u32 (8 slots x 16B)
    const int srow = tid >> 4;
    const int ssu  = tid & 15;
    const float* xg = x + (size_t)(rb + srow) * D_MODEL + ssu * 4;
    const int xw_off = srow * 32 + (((ssu >> 1) ^ (srow & 7)) << 2) + ((ssu & 1) << 1);

    const int mt = wv >> 2, nt = wv & 3;
    const int arow = mt * 16 + (lane & 15);
    const int be   = nt * 16 + (lane & 15);
    const int kq   = lane >> 4;
    const int ap = arow & 7, bp = be & 7;

    f32x4 accA = {0.f,0.f,0.f,0.f}, accB = {0.f,0.f,0.f,0.f};

    #define XPLANE_WRITE(dstbase, p)                                         \
    {                                                                        \
        _Float16 h0=(_Float16)((p).x*256.f), h1=(_Float16)((p).y*256.f),     \
                 h2=(_Float16)((p).z*256.f), h3=(_Float16)((p).w*256.f);     \
        _Float16 l0=(_Float16)((p).x*256.f-(float)h0),                       \
                 l1=(_Float16)((p).y*256.f-(float)h1),                       \
                 l2=(_Float16)((p).z*256.f-(float)h2),                       \
                 l3=(_Float16)((p).w*256.f-(float)h3);                       \
        union { _Float16 f[2]; uint32_t u; } t0,t1,t2,t3;                    \
        t0.f[0]=h0; t0.f[1]=h1; t1.f[0]=h2; t1.f[1]=h3;                      \
        t2.f[0]=l0; t2.f[1]=l1; t3.f[0]=l2; t3.f[1]=l3;                      \
        *(uint2*)((dstbase) + xw_off)        = make_uint2(t0.u, t1.u);       \
        *(uint2*)((dstbase) + 1024 + xw_off) = make_uint2(t2.u, t3.u);       \
    }

    {
        const float4 p0 = *(const float4*)xg;
        XPLANE_WRITE(lx, p0);
        GLD16(wimg + (size_t)tid * 4,         lw + tid * 4);
        GLD16(wimg + (size_t)(tid + 512) * 4, lw + (tid + 512) * 4);
    }
    float4 px = *(const float4*)(xg + BK);
    BAR_KEEP1();

    for (int t = 0; t < NCH; ++t) {
        const int buf = t & 1, nbuf = buf ^ 1;

        if (t + 1 < NCH) {
            const uint32_t* ws = wimg + (size_t)(t + 1) * 4096;
            GLD16(ws + (size_t)tid * 4,         lw + nbuf * 4096 + tid * 4);
            GLD16(ws + (size_t)(tid + 512) * 4, lw + (size_t)nbuf * 4096 + (tid + 512) * 4);
        }

        const uint32_t* lxb = lx + buf * 2048;
        const uint32_t* lwb = lw + buf * 4096;
        {
            F8 ah, al, bh, bl;
            // ks = 0 -> accA chain
            ah.v = *(const f16x8*)(lxb +        arow * 32 + (((0 * 4 + kq) ^ ap) << 2));
            al.v = *(const f16x8*)(lxb + 1024 + arow * 32 + (((0 * 4 + kq) ^ ap) << 2));
            bh.v = *(const f16x8*)(lwb +        (be * 8 + ((0 * 4 + kq) ^ bp)) * 4);
            bl.v = *(const f16x8*)(lwb + 2048 + (be * 8 + ((0 * 4 + kq) ^ bp)) * 4);
            accA = __builtin_amdgcn_mfma_f32_16x16x32_f16(ah.v, bh.v, accA, 0, 0, 0);
            accA = __builtin_amdgcn_mfma_f32_16x16x32_f16(ah.v, bl.v, accA, 0, 0, 0);
            accA = __builtin_amdgcn_mfma_f32_16x16x32_f16(al.v, bh.v, accA, 0, 0, 0);
            // ks = 1 -> accB chain (independent)
            ah.v = *(const f16x8*)(lxb +        arow * 32 + (((1 * 4 + kq) ^ ap) << 2));
            al.v = *(const f16x8*)(lxb + 1024 + arow * 32 + (((1 * 4 + kq) ^ ap) << 2));
            bh.v = *(const f16x8*)(lwb +        (be * 8 + ((1 * 4 + kq) ^ bp)) * 4);
            bl.v = *(const f16x8*)(lwb + 2048 + (be * 8 + ((1 * 4 + kq) ^ bp)) * 4);
            accB = __builtin_amdgcn_mfma_f32_16x16x32_f16(ah.v, bh.v, accB, 0, 0, 0);
            accB = __builtin_amdgcn_mfma_f32_16x16x32_f16(ah.v, bl.v, accB, 0, 0, 0);
            accB = __builtin_amdgcn_mfma_f32_16x16x32_f16(al.v, bh.v, accB, 0, 0, 0);
        }

        if (t + 1 < NCH) {
            XPLANE_WRITE(lx + nbuf * 2048, px);
            if (t + 2 < NCH) px = *(const float4*)(xg + (size_t)(t + 2) * BK);
        }

        if (t + 2 < NCH) { BAR_KEEP1(); } else { BAR_FULL(); }
    }
    #undef XPLANE_WRITE

    #pragma unroll
    for (int r = 0; r < 4; ++r) {
        const int row = mt * 16 + kq * 4 + r;
        ll[row * 68 + be] = (accA[r] + accB[r]) * (1.0f / 262144.0f);
    }
    __syncthreads();

    float pi_acc = 0.f, cnt_acc = 0.f;
    for (int rr = 0; rr < 4; ++rr) {
        const int row = wv * 4 + rr;
        const float lg = ll[row * 68 + lane];

        float m = lg;
        #pragma unroll
        for (int off = 32; off; off >>= 1) m = fmaxf(m, __shfl_xor(m, off));
        const float e = expf(lg - m);
        float s = e;
        #pragma unroll
        for (int off = 32; off; off >>= 1) s += __shfl_xor(s, off);
        const float score = e / s;

        float v1 = score; int i1 = lane;
        #pragma unroll
        for (int off = 32; off; off >>= 1) {
            const float ov = __shfl_xor(v1, off);
            const int   oi = __shfl_xor(i1, off);
            if (ov > v1 || (ov == v1 && oi < i1)) { v1 = ov; i1 = oi; }
        }
        float v2 = (lane == i1) ? -1.f : score; int i2 = lane;
        #pragma unroll
        for (int off = 32; off; off >>= 1) {
            const float ov = __shfl_xor(v2, off);
            const int   oi = __shfl_xor(i2, off);
            if (ov > v2 || (ov == v2 && oi < i2)) { v2 = ov; i2 = oi; }
        }

        if (lane == 0) {
            const int grow = rb + row;
            const float denom = v1 + v2 + 1e-9f;
            out_w[grow * 2 + 0] = v1 / denom;
            out_w[grow * 2 + 1] = v2 / denom;
            out_i[grow * 2 + 0] = (float)i1;
            out_i[grow * 2 + 1] = (float)i2;
        }
        pi_acc  += score;
        cnt_acc += (float)((lane == i1) + (lane == i2));
    }

    apx[wv][lane] = pi_acc;
    acn[wv][lane] = cnt_acc;
    __syncthreads();

    if (tid < NE) {
        float p = 0.f, c = 0.f;
        #pragma unroll
        for (int w = 0; w < 8; ++w) { p += apx[w][tid]; c += acn[w][tid]; }
        atomicAdd(&g_pi[tid],  p);
        atomicAdd(&g_cnt[tid], c);
    }
}

__global__ void router_finalize(const float* __restrict__ g_pi,
                                const float* __restrict__ g_cnt,
                                float* __restrict__ aux_out) {
    const int lane = threadIdx.x;  // 64
    const float pi = g_pi[lane] * (1.0f / (float)N_ROWS);
    const float fi = g_cnt[lane] * (64.0f / (float)(N_ROWS * 2));
    float v = pi * fi;
    #pragma unroll
    for (int off = 32; off; off >>= 1) v += __shfl_xor(v, off);
    if (lane == 0) aux_out[0] = v * ALPHA;
}

extern "C" void kernel_launch(void* const* d_in, const int* in_sizes, int n_in,
                              void* d_out, int out_size, void* d_ws, size_t ws_size,
                              hipStream_t stream) {
    const float* x = (const float*)d_in[0];
    const float* W = (const float*)d_in[1];

    float* out   = (float*)d_out;
    float* out_w = out;                   // [N,2]
    float* out_i = out + N_ROWS * 2;      // [N,2] as float
    float* aux   = out + N_ROWS * 4;      // [1]

    float*    g_pi  = (float*)d_ws;               // [64]
    float*    g_cnt = g_pi + NE;                  // [64]
    uint32_t* wimg  = (uint32_t*)d_ws + 256;      // [32][4096] = 512 KB W plane image

    // B-variant scratch (unvalidated): placed past wimg (ends at byte ~525k)
    float* out_wB = (float*)d_ws + 140000;        // [N,2]
    float* out_iB = out_wB + N_ROWS * 2;          // [N,2]
    float* g_piB  = out_iB + N_ROWS * 2;          // [64]
    float* g_cntB = g_piB + NE;                   // [64]

    hipMemsetAsync(d_ws, 0, 512, stream);

    w_prep<<<dim3(256), dim3(256), 0, stream>>>(W, wimg);
    router_mfma<<<dim3(N_ROWS / BR), dim3(THREADS), 0, stream>>>(
        x, wimg, out_w, out_i, g_pi, g_cnt);
    router_finalize<<<dim3(1), dim3(64), 0, stream>>>(g_pi, g_cnt, aux);
    router_mfma_b<<<dim3(N_ROWS / BR), dim3(THREADS), 0, stream>>>(
        x, wimg, out_wB, out_iB, g_piB, g_cntB);
}